// Round 11
// baseline (286.836 us; speedup 1.0000x reference)
//
#include <hip/hip_runtime.h>

using uint = unsigned int;
typedef short bf16x8 __attribute__((ext_vector_type(8)));
typedef _Float16 f16x8 __attribute__((ext_vector_type(8)));
typedef float f32x4 __attribute__((ext_vector_type(4)));
typedef long i64;
typedef i64 i64x2 __attribute__((ext_vector_type(2)));
typedef i64 i64x4 __attribute__((ext_vector_type(4)));
typedef int i32x8 __attribute__((ext_vector_type(8)));
typedef unsigned short u16x4 __attribute__((ext_vector_type(4)));

static constexpr int Cc = 512;
static constexpr int Nn = 4096;               // H*W
static constexpr size_t NC = (size_t)Nn * Cc; // 2097152 elements
static constexpr size_t SN = (size_t)Nn * Nn; // 16777216 elements

__device__ __forceinline__ unsigned short f2bf(float f) {
    unsigned int u = __builtin_bit_cast(unsigned int, f);
    u = (u + 0x7fff + ((u >> 16) & 1)) >> 16;
    return (unsigned short)u;
}
__device__ __forceinline__ unsigned short f2h(float f) {
    _Float16 h = (_Float16)f;
    return __builtin_bit_cast(unsigned short, h);
}

// sigma: element permutation within 64-element groups (4x4 chunk transpose).
// Used for S/V j-dim (fp8) and o_t/wo c-dim (bf16): producers' per-lane values
// land contiguous, consumers contract position-wise (invariant).
__device__ __forceinline__ int sig64(int j) {
    return (j & ~63) | (((j >> 2) & 3) << 4) | (((j >> 4) & 3) << 2) | (j & 3);
}

__device__ __forceinline__ void gll16(const void* g, void* l) {
    __builtin_amdgcn_global_load_lds(
        (const __attribute__((address_space(1))) void*)g,
        (__attribute__((address_space(3))) void*)l, 16, 0, 0);
}

// Unit-scale (E8M0 = 127 -> 2^0) MX fp8 MFMA, K=128 per instruction.
__device__ __forceinline__ f32x4 mfma_fp8_k128(i32x8 a, i32x8 b, f32x4 c) {
    return __builtin_amdgcn_mfma_scale_f32_16x16x128_f8f6f4(
        a, b, c, 0 /*A=fp8*/, 0 /*B=fp8*/, 0, 0x7F7F7F7F, 0, 0x7F7F7F7F);
}

// 32B fragment from a 128B-row LDS tile with granule swizzle g^(R&7):
// two i64x2 loads (ds_read_b128), register combine.
__device__ __forceinline__ i32x8 ld_frag256(const unsigned char* base, int R, int g0) {
    const unsigned char* p = base + R * 128;
    i64x2 l0 = *(const i64x2*)(p + ((g0 ^ (R & 7)) << 4));
    i64x2 l1 = *(const i64x2*)(p + (((g0 + 1) ^ (R & 7)) << 4));
    i64x4 c4 = {l0[0], l0[1], l1[0], l1[1]};
    return __builtin_bit_cast(i32x8, c4);
}

// ---------------- zero the GN partial-sum accumulators ----------------
__global__ void zero_kernel(float* __restrict__ p, int n4) {
    int i = blockIdx.x * blockDim.x + threadIdx.x;
    if (i < n4) ((float4*)p)[i] = make_float4(0.f, 0.f, 0.f, 0.f);
}

// ---------------- fp32 -> bf16 weight convert (all 4 weights, y = which) --------
// wo (y==3) gets sig64-permuted k-columns to match o_t's sig64 c-layout.
__global__ void cvt4_kernel(const float* __restrict__ wa, const float* __restrict__ wb,
                            const float* __restrict__ wc, const float* __restrict__ wd,
                            unsigned short* __restrict__ out) {
    const float* ins[4] = {wa, wb, wc, wd};
    const float* in = ins[blockIdx.y];
    unsigned short* o = out + (size_t)blockIdx.y * 262144;
    int i = blockIdx.x * blockDim.x + threadIdx.x; // 0..65535 float4s
    float4 v = ((const float4*)in)[i];
    int e = i * 4;
    int idx;
    if (blockIdx.y == 3) {
        int m = e >> 9, k = e & 511;           // k&3 == 0
        int kp = (k & ~63) | (((k >> 2) & 3) << 4) | (((k >> 4) & 3) << 2);
        idx = m * 512 + kp;
    } else {
        idx = e;
    }
    o[idx + 0] = f2bf(v.x);
    o[idx + 1] = f2bf(v.y);
    o[idx + 2] = f2bf(v.z);
    o[idx + 3] = f2bf(v.w);
}

// ---------------- GN pass 1: partial sums per (b,g), 8 sub-blocks each ----------
// 1024 blocks (4 blocks/CU) instead of 128 (0.5/CU): BW-bound kernel needs the
// whole chip. Raw sum/sumsq accumulated via f32 atomics; finalized in gn_norm.
__global__ void gn_stats_kernel(const float* __restrict__ x, float* __restrict__ sums,
                                float* __restrict__ sqs) {
    int bid = blockIdx.x;          // 1024 = 128 bg * 8 sub
    int bg = bid >> 3, sub = bid & 7;
    const float4* s4 = (const float4*)(x + (size_t)bg * 65536) + sub * 2048;
    int t = threadIdx.x; // 256
    float s1 = 0.f, s2 = 0.f;
#pragma unroll
    for (int k = 0; k < 8; ++k) {
        float4 v = s4[k * 256 + t];
        s1 += v.x + v.y + v.z + v.w;
        s2 += v.x * v.x + v.y * v.y + v.z * v.z + v.w * v.w;
    }
#pragma unroll
    for (int o = 32; o > 0; o >>= 1) { s1 += __shfl_down(s1, o); s2 += __shfl_down(s2, o); }
    __shared__ float r1[4], r2[4];
    int wv_ = t >> 6, ln = t & 63;
    if (ln == 0) { r1[wv_] = s1; r2[wv_] = s2; }
    __syncthreads();
    if (t == 0) {
        atomicAdd(&sums[bg], r1[0] + r1[1] + r1[2] + r1[3]);
        atomicAdd(&sqs[bg], r2[0] + r2[1] + r2[2] + r2[3]);
    }
}

// ---------------- GN pass 2: normalize + transpose via LDS tile ----------------
__global__ __launch_bounds__(256) void gn_norm_kernel(
    const float* __restrict__ x, const float* __restrict__ sums, const float* __restrict__ sqs,
    const float* __restrict__ gamma, const float* __restrict__ beta,
    unsigned short* __restrict__ h_t) {
    __shared__ float tile[64][65];
    int n0 = blockIdx.x * 64, c0 = blockIdx.y * 64, b = blockIdx.z;
    int t = threadIdx.x;
    const float* xb = x + (size_t)b * Cc * Nn;
#pragma unroll
    for (int j = 0; j < 4; ++j) {
        int i = j * 256 + t;
        int c = i >> 4;       // 0..63
        int n4 = i & 15;      // float4 index within row
        int cg = c0 + c;
        float4 v = ((const float4*)(xb + (size_t)cg * Nn + n0))[n4];
        int g = cg >> 4;
        float sm = sums[b * 32 + g], sq = sqs[b * 32 + g];
        float mean = sm * (1.f / 65536.f);
        float var = sq * (1.f / 65536.f) - mean * mean;
        float rs = rsqrtf(var + 1e-6f);
        float ga = gamma[cg] * rs;
        float be = beta[cg] - mean * ga;
        tile[n4 * 4 + 0][c] = v.x * ga + be;
        tile[n4 * 4 + 1][c] = v.y * ga + be;
        tile[n4 * 4 + 2][c] = v.z * ga + be;
        tile[n4 * 4 + 3][c] = v.w * ga + be;
    }
    __syncthreads();
    int n = t >> 2;                 // 0..63
    int cpart = (t & 3) * 16;       // 0,16,32,48
    unsigned short o[16];
#pragma unroll
    for (int q = 0; q < 16; ++q) o[q] = f2bf(tile[n][cpart + q]);
    unsigned short* dst = h_t + (size_t)b * NC + (size_t)(n0 + n) * Cc + c0 + cpart;
    ((uint4*)dst)[0] = ((uint4*)o)[0];
    ((uint4*)dst)[1] = ((uint4*)o)[1];
}

// ---------------- bf16 GEMM: out[M,N] = (A[M,K] * Bt[N,K]^T + bias) * alpha (+res) --------
// Block tile BM x 128, 4 waves as 2x2, wave tile (BM/2) x 64. BK=64.
// Optional column split (nsplit>0): blocks with n0>=nsplit write outp2/bias2 at col-nsplit.
// OUT_MODE: 0 fp32, 1 bf16, 2 fp16, 3 fp8 natural cols, 4 fp8 sig64-permuted cols.
template <int BM, int DT, int BIAS_MODE, int OUT_MODE, int HAS_RES>
__global__ __launch_bounds__(256, 2) void gemm_bt(
    const unsigned short* __restrict__ A, int lda, size_t sA,
    const unsigned short* __restrict__ Bt, int ldb, size_t sB,
    void* __restrict__ outp, int ldc, size_t sC,
    const float* __restrict__ bias,
    const float* __restrict__ res, size_t sR,
    int K, float alpha,
    const float* __restrict__ bias2, void* __restrict__ outp2, int nsplit) {
    constexpr int MT = BM / 32;  // m-fragments per wave (4 or 8)
    __shared__ unsigned short lA[BM * 64];
    __shared__ unsigned short lB[128 * 64];
    int z = blockIdx.z;
    A += (size_t)z * sA;
    Bt += (size_t)z * sB;
    int m0 = blockIdx.y * BM, n0 = blockIdx.x * 128;
    int ncol0 = n0;
    if (nsplit && n0 >= nsplit) { bias = bias2; outp = outp2; ncol0 = n0 - nsplit; }
    int t = threadIdx.x;
    int lane = t & 63, wave = t >> 6;
    int wm = wave >> 1, wn = wave & 1;
    int lo = lane & 15, quad = lane >> 4;

    f32x4 acc[MT][4];
#pragma unroll
    for (int a1 = 0; a1 < MT; ++a1)
#pragma unroll
        for (int a2 = 0; a2 < 4; ++a2) acc[a1][a2] = (f32x4){0.f, 0.f, 0.f, 0.f};

    for (int k0 = 0; k0 < K; k0 += 64) {
#pragma unroll
        for (int p = 0; p < MT; ++p) {
            int ci = p * 256 + t;
            int row = ci >> 3;
            int gs = (ci ^ row) & 7;  // swizzled granule
            gll16(A + (size_t)(m0 + row) * lda + k0 + gs * 8, &lA[(size_t)ci * 8]);
        }
#pragma unroll
        for (int p = 0; p < 4; ++p) {
            int ci = p * 256 + t;
            int row = ci >> 3;
            int gs = (ci ^ row) & 7;
            gll16(Bt + (size_t)(n0 + row) * ldb + k0 + gs * 8, &lB[(size_t)ci * 8]);
        }
        __syncthreads();
#pragma unroll
        for (int ks = 0; ks < 2; ++ks) {
            int G = quad + ks * 4;  // granule index (8 halfs each)
            bf16x8 af[MT], bfr[4];
#pragma unroll
            for (int mt = 0; mt < MT; ++mt) {
                int R = wm * (BM / 2) + mt * 16 + lo;
                af[mt] = *(const bf16x8*)&lA[R * 64 + (((G ^ R) & 7) << 3)];
            }
#pragma unroll
            for (int nt = 0; nt < 4; ++nt) {
                int R = wn * 64 + nt * 16 + lo;
                bfr[nt] = *(const bf16x8*)&lB[R * 64 + (((G ^ R) & 7) << 3)];
            }
#pragma unroll
            for (int mt = 0; mt < MT; ++mt)
#pragma unroll
                for (int nt = 0; nt < 4; ++nt) {
                    if (DT == 0)
                        acc[mt][nt] = __builtin_amdgcn_mfma_f32_16x16x32_bf16(af[mt], bfr[nt], acc[mt][nt], 0, 0, 0);
                    else
                        acc[mt][nt] = __builtin_amdgcn_mfma_f32_16x16x32_f16(
                            __builtin_bit_cast(f16x8, af[mt]), __builtin_bit_cast(f16x8, bfr[nt]),
                            acc[mt][nt], 0, 0, 0);
                }
        }
        __syncthreads();
    }

    size_t zc = (size_t)z * sC;
    float* outf = (float*)outp + zc;
    unsigned short* outb = (unsigned short*)outp + zc;
    unsigned char* outc = (unsigned char*)outp + zc;
    const float* resz = HAS_RES ? res + (size_t)z * sR : nullptr;

#pragma unroll
    for (int mt = 0; mt < MT; ++mt) {
#pragma unroll
        for (int nt = 0; nt < 4; ++nt) {
            int row = m0 + wm * (BM / 2) + mt * 16 + quad * 4;
            int col = ncol0 + wn * 64 + nt * 16 + lo;
            float bn = (BIAS_MODE == 2) ? bias[col] : 0.f;
#pragma unroll
            for (int r = 0; r < 4; ++r) {
                float vv = acc[mt][nt][r];
                if (BIAS_MODE == 1) vv += bias[row + r];
                if (BIAS_MODE == 2) vv += bn;
                vv *= alpha;
                if (OUT_MODE == 3 || OUT_MODE == 4) {
                    float e = fmaxf(fminf(vv, 448.f), -448.f);
                    int pk = __builtin_amdgcn_cvt_pk_fp8_f32(e, e, 0, false);
                    int cp = (OUT_MODE == 4) ? sig64(col) : col;
                    outc[(size_t)(row + r) * ldc + cp] = (unsigned char)(pk & 0xff);
                } else {
                    size_t off = (size_t)(row + r) * ldc + col;
                    if (HAS_RES) vv += resz[off];
                    if (OUT_MODE == 0) outf[off] = vv;
                    else if (OUT_MODE == 1) outb[off] = f2bf(vv);
                    else outb[off] = f2h(vv);
                }
            }
        }
    }
}

// ---------------- QK: S = fp8(exp((Q.K^T)*alpha - 2)), sig64 j-layout ----------------
// Q,K fp8 [B,N,C] natural k-layout. Block 128x128, 4 waves 2x2 (64x64 each), BK=128.
// Swapped operands: D = mfma(K, Q). Lane's 16 values per qt contiguous under sig64
// -> one uint4 store per qt. Row sums computed in pv via ones-MFMA.
__global__ __launch_bounds__(256, 3) void qk_fp8(
    const unsigned char* __restrict__ Q, const unsigned char* __restrict__ Kt,
    unsigned char* __restrict__ S, float alpha) {
    __shared__ unsigned char lA[128 * 128]; // Q tile, 16 KB
    __shared__ unsigned char lB[128 * 128]; // K tile, 16 KB
    int z = blockIdx.z;
    Q += (size_t)z * NC;
    Kt += (size_t)z * NC;
    S += (size_t)z * SN;
    int m0 = blockIdx.y * 128, n0 = blockIdx.x * 128;
    int t = threadIdx.x;
    int lane = t & 63, wave = t >> 6;
    int wm = wave >> 1, wn = wave & 1;
    int lo = lane & 15, quad = lane >> 4;

    f32x4 acc[4][4]; // [jt][qt]
#pragma unroll
    for (int a1 = 0; a1 < 4; ++a1)
#pragma unroll
        for (int a2 = 0; a2 < 4; ++a2) acc[a1][a2] = (f32x4){0.f, 0.f, 0.f, 0.f};

    for (int k0 = 0; k0 < Cc; k0 += 128) {
#pragma unroll
        for (int p = 0; p < 4; ++p) {
            int ci = p * 256 + t;
            int row = ci >> 3, g = ci & 7;
            int gs = g ^ (row & 7);
            gll16(Q + (size_t)(m0 + row) * Cc + k0 + gs * 16, &lA[ci * 16]);
        }
#pragma unroll
        for (int p = 0; p < 4; ++p) {
            int ci = p * 256 + t;
            int row = ci >> 3, g = ci & 7;
            int gs = g ^ (row & 7);
            gll16(Kt + (size_t)(n0 + row) * Cc + k0 + gs * 16, &lB[ci * 16]);
        }
        __syncthreads();
        int g0 = quad * 2;  // lane quad consumes k-bytes [quad*32, quad*32+32)
        i32x8 qf[4];        // B-operand: Q fragments
#pragma unroll
        for (int qt = 0; qt < 4; ++qt) qf[qt] = ld_frag256(lA, wm * 64 + qt * 16 + lo, g0);
        __builtin_amdgcn_s_setprio(1);
#pragma unroll
        for (int jt = 0; jt < 4; ++jt) {
            i32x8 kf = ld_frag256(lB, wn * 64 + jt * 16 + lo, g0); // A-operand: K fragment
#pragma unroll
            for (int qt = 0; qt < 4; ++qt)
                acc[jt][qt] = mfma_fp8_k128(kf, qf[qt], acc[jt][qt]);
        }
        __builtin_amdgcn_s_setprio(0);
        __syncthreads();
    }

    // Epilogue: lane (lo,quad) holds S[q][j = n0+wn*64+jt*16+quad*4+r]; under sig64
    // those 16 values are bytes [quad*16, quad*16+16) of the 64-group -> one uint4/qt.
    const float L2E = 1.4426950408889634f;
    float a2 = alpha * L2E;
    float b2 = -2.f * L2E;
#pragma unroll
    for (int qt = 0; qt < 4; ++qt) {
        int q = m0 + wm * 64 + qt * 16 + lo;
        uint w[4];
#pragma unroll
        for (int jt = 0; jt < 4; ++jt) {
            float e0 = fminf(exp2f(fmaf(acc[jt][qt][0], a2, b2)), 448.f);
            float e1 = fminf(exp2f(fmaf(acc[jt][qt][1], a2, b2)), 448.f);
            float e2 = fminf(exp2f(fmaf(acc[jt][qt][2], a2, b2)), 448.f);
            float e3 = fminf(exp2f(fmaf(acc[jt][qt][3], a2, b2)), 448.f);
            int d = __builtin_amdgcn_cvt_pk_fp8_f32(e0, e1, 0, false);
            d = __builtin_amdgcn_cvt_pk_fp8_f32(e2, e3, d, true);
            w[jt] = (uint)d;
        }
        *(uint4*)&S[(size_t)q * Nn + n0 + wn * 64 + quad * 16] =
            make_uint4(w[0], w[1], w[2], w[3]);
    }
}

// ---------------- PV: o_t[q,c] = (sum_j P[q,j] V[c,j]) / rowsum(P[q,:]) ----------------
// S [B,N,N] and V [B,C,N] BOTH in sig64 j-layout -> contraction position-wise.
// Row sums via ones-MFMA. o_t written in sig64 c-layout (matched by permuted wob):
// lane's 16 bf16 contiguous -> 2x uint4 stores per qt, full 128B lines per wave instr.
__global__ __launch_bounds__(256, 3) void pv_fp8(
    const unsigned char* __restrict__ S, const unsigned char* __restrict__ V,
    unsigned short* __restrict__ o_t) {
    __shared__ unsigned char lA[128 * 128]; // S tile (q rows)
    __shared__ unsigned char lB[128 * 128]; // V tile (c rows)
    int z = blockIdx.z;
    S += (size_t)z * SN;
    V += (size_t)z * NC;
    o_t += (size_t)z * NC;
    int m0 = blockIdx.y * 128, n0 = blockIdx.x * 128;
    int t = threadIdx.x;
    int lane = t & 63, wave = t >> 6;
    int wm = wave >> 1, wn = wave & 1;
    int lo = lane & 15, quad = lane >> 4;

    f32x4 acc[4][4]; // [ct][qt]
    f32x4 rs[4];     // [qt] row-sum accumulators
#pragma unroll
    for (int a1 = 0; a1 < 4; ++a1) {
        rs[a1] = (f32x4){0.f, 0.f, 0.f, 0.f};
#pragma unroll
        for (int a2 = 0; a2 < 4; ++a2) acc[a1][a2] = (f32x4){0.f, 0.f, 0.f, 0.f};
    }
    const int OB = 0x38383838; // 4x fp8 e4m3 1.0
    const i32x8 ones = {OB, OB, OB, OB, OB, OB, OB, OB};

    for (int k0 = 0; k0 < Nn; k0 += 128) {
#pragma unroll
        for (int p = 0; p < 4; ++p) {
            int ci = p * 256 + t;
            int row = ci >> 3, g = ci & 7;
            int gs = g ^ (row & 7);
            gll16(S + (size_t)(m0 + row) * Nn + k0 + gs * 16, &lA[ci * 16]);
        }
#pragma unroll
        for (int p = 0; p < 4; ++p) {
            int ci = p * 256 + t;
            int row = ci >> 3, g = ci & 7;
            int gs = g ^ (row & 7);
            gll16(V + (size_t)(n0 + row) * Nn + k0 + gs * 16, &lB[ci * 16]);
        }
        __syncthreads();
        int g0 = quad * 2;
        i32x8 sf[4]; // B-operand: S fragments (q rows)
        __builtin_amdgcn_s_setprio(1);
#pragma unroll
        for (int qt = 0; qt < 4; ++qt) {
            sf[qt] = ld_frag256(lA, wm * 64 + qt * 16 + lo, g0);
            rs[qt] = mfma_fp8_k128(ones, sf[qt], rs[qt]);
        }
#pragma unroll
        for (int ct = 0; ct < 4; ++ct) {
            i32x8 vf = ld_frag256(lB, wn * 64 + ct * 16 + lo, g0); // A-operand: V fragment
#pragma unroll
            for (int qt = 0; qt < 4; ++qt)
                acc[ct][qt] = mfma_fp8_k128(vf, sf[qt], acc[ct][qt]);
        }
        __builtin_amdgcn_s_setprio(0);
        __syncthreads();
    }

    // Epilogue: lane holds o_t[q][c = n0+wn*64+ct*16+quad*4+r]; under sig64 on the
    // c-dim those 16 bf16 are elements [quad*16, quad*16+16) of the 64-group.
#pragma unroll
    for (int qt = 0; qt < 4; ++qt) {
        int q = m0 + wm * 64 + qt * 16 + lo;
        float inv = 1.f / rs[qt][0];
        unsigned short o16[16];
#pragma unroll
        for (int ct = 0; ct < 4; ++ct)
#pragma unroll
            for (int r = 0; r < 4; ++r)
                o16[ct * 4 + r] = f2bf(acc[ct][qt][r] * inv);
        unsigned short* dst = &o_t[(size_t)q * Cc + n0 + wn * 64 + quad * 16];
        ((uint4*)dst)[0] = ((uint4*)o16)[0];
        ((uint4*)dst)[1] = ((uint4*)o16)[1];
    }
}

extern "C" void kernel_launch(void* const* d_in, const int* in_sizes, int n_in,
                              void* d_out, int out_size, void* d_ws, size_t ws_size,
                              hipStream_t stream) {
    const float* x     = (const float*)d_in[0];
    const float* gamma = (const float*)d_in[1];
    const float* beta  = (const float*)d_in[2];
    const float* wq = (const float*)d_in[3];
    const float* bq = (const float*)d_in[4];
    const float* wk = (const float*)d_in[5];
    const float* bk = (const float*)d_in[6];
    const float* wv = (const float*)d_in[7];
    const float* bv = (const float*)d_in[8];
    const float* wo = (const float*)d_in[9];
    const float* bo = (const float*)d_in[10];

    char* ws = (char*)d_ws;
    unsigned short* h_t  = (unsigned short*)(ws);                 // [B,N,C] bf16 16MB
    unsigned char*  q_8  = (unsigned char*)(ws + 16777216);       // [B,N,C] fp8
    unsigned char*  k_8  = (unsigned char*)(ws + 33554432);       // [B,N,C] fp8
    unsigned char*  v_8  = (unsigned char*)(ws + 50331648);       // [B,C,N] fp8 sig64
    unsigned short* o_t  = (unsigned short*)(ws + 67108864);      // [B,N,C] bf16 sig64-c
    unsigned char*  S    = (unsigned char*)(ws + 83886080);       // [B,N,N] fp8 sig64 67MB
    unsigned short* wqb  = (unsigned short*)(ws + 218103808);     // wq,wk,wv,wo bf16 contiguous
    unsigned short* wvb  = (unsigned short*)(ws + 219152384);
    unsigned short* wob  = (unsigned short*)(ws + 219676672);     // sig64-k layout
    float* statm         = (float*)(ws + 220200960);              // [128] GN sum
    float* statr         = (float*)(ws + 220201984);              // [128] GN sumsq
    // zero region covers statm..statr: [220200960, 220203008) = 2048 B = 128 float4

    const float SCALE = 0.044194173824159216f; // 512^-0.5

    zero_kernel<<<1, 128, 0, stream>>>(statm, 128); // zeroes statm gap statr (2 KB)

    // all 4 weight converts in one launch (wqb/wkb/wvb/wob contiguous, 262144 elems apart)
    cvt4_kernel<<<dim3(256, 4), 256, 0, stream>>>(wq, wk, wv, wo, wqb);

    gn_stats_kernel<<<1024, 256, 0, stream>>>(x, statm, statr);
    gn_norm_kernel<<<dim3(64, 8, 4), 256, 0, stream>>>(x, statm, statr, gamma, beta, h_t);

    // q_8 | k_8 = fp8(h . [Wq;Wk]^T + [bq;bk])  [B,N,C] in ONE launch (col split at 512)
    gemm_bt<128, 0, 2, 3, 0><<<dim3(8, 32, 4), 256, 0, stream>>>(
        h_t, Cc, NC, wqb, Cc, 0, q_8, Cc, NC, bq, nullptr, 0, Cc, 1.f, bk, k_8, 512);
    // v_8 = fp8(Wv . h^T + bv)   [B,C,N] sig64 j-layout (matches S)
    gemm_bt<128, 0, 1, 4, 0><<<dim3(32, 4, 4), 256, 0, stream>>>(
        wvb, Cc, 0, h_t, Cc, NC, v_8, Nn, NC, bv, nullptr, 0, Cc, 1.f, nullptr, nullptr, 0);

    // S = fp8(exp(q.k^T * scale - 2)), sig64 j-layout
    qk_fp8<<<dim3(32, 32, 4), 256, 0, stream>>>(q_8, k_8, S, SCALE);
    // o_t = (S . V^T) / rowsum(S)   bf16 [B,N,C] sig64-c  (row sums via ones-MFMA)
    pv_fp8<<<dim3(4, 32, 4), 256, 0, stream>>>(S, v_8, o_t);

    // out = Wo . o^T + bo + x   fp32 [B,C,N]  (wob and o_t share sig64 k-layout)
    gemm_bt<128, 0, 1, 0, 1><<<dim3(32, 4, 4), 256, 0, stream>>>(
        wob, Cc, 0, o_t, Cc, NC, d_out, Nn, NC, bo, x, NC, Cc, 1.f, nullptr, nullptr, 0);
}

// Round 13
// 271.756 us; speedup vs baseline: 1.0555x; 1.0555x over previous
//
#include <hip/hip_runtime.h>

using uint = unsigned int;
typedef short bf16x8 __attribute__((ext_vector_type(8)));
typedef _Float16 f16x8 __attribute__((ext_vector_type(8)));
typedef float f32x4 __attribute__((ext_vector_type(4)));
typedef long i64;
typedef i64 i64x2 __attribute__((ext_vector_type(2)));
typedef i64 i64x4 __attribute__((ext_vector_type(4)));
typedef int i32x8 __attribute__((ext_vector_type(8)));
typedef unsigned short u16x4 __attribute__((ext_vector_type(4)));

static constexpr int Cc = 512;
static constexpr int Nn = 4096;               // H*W
static constexpr size_t NC = (size_t)Nn * Cc; // 2097152 elements
static constexpr size_t SN = (size_t)Nn * Nn; // 16777216 elements

__device__ __forceinline__ unsigned short f2bf(float f) {
    unsigned int u = __builtin_bit_cast(unsigned int, f);
    u = (u + 0x7fff + ((u >> 16) & 1)) >> 16;
    return (unsigned short)u;
}
__device__ __forceinline__ unsigned short f2h(float f) {
    _Float16 h = (_Float16)f;
    return __builtin_bit_cast(unsigned short, h);
}

// sigma: element permutation within 64-element groups (4x4 chunk transpose).
// Used for S/V j-dim (fp8) and o_t/wo c-dim (bf16): producers' per-lane values
// land contiguous, consumers contract position-wise (invariant).
__device__ __forceinline__ int sig64(int j) {
    return (j & ~63) | (((j >> 2) & 3) << 4) | (((j >> 4) & 3) << 2) | (j & 3);
}

__device__ __forceinline__ void gll16(const void* g, void* l) {
    __builtin_amdgcn_global_load_lds(
        (const __attribute__((address_space(1))) void*)g,
        (__attribute__((address_space(3))) void*)l, 16, 0, 0);
}

// 32B fragment from a 128B-row LDS tile with granule swizzle g^(R&7):
// two i64x2 loads (ds_read_b128), register combine.
__device__ __forceinline__ i32x8 ld_frag256(const unsigned char* base, int R, int g0) {
    const unsigned char* p = base + R * 128;
    i64x2 l0 = *(const i64x2*)(p + ((g0 ^ (R & 7)) << 4));
    i64x2 l1 = *(const i64x2*)(p + (((g0 + 1) ^ (R & 7)) << 4));
    i64x4 c4 = {l0[0], l0[1], l1[0], l1[1]};
    return __builtin_bit_cast(i32x8, c4);
}

// Unit-scale (E8M0 = 127 -> 2^0) MX fp8 MFMA, K=128 per instruction.
__device__ __forceinline__ f32x4 mfma_fp8_k128v(i32x8 a, i32x8 b, f32x4 c) {
    return __builtin_amdgcn_mfma_scale_f32_16x16x128_f8f6f4(
        a, b, c, 0 /*A=fp8*/, 0 /*B=fp8*/, 0, 0x7F7F7F7F, 0, 0x7F7F7F7F);
}

// ---------------- zero the GN partial-sum accumulators ----------------
__global__ void zero_kernel(float* __restrict__ p, int n4) {
    int i = blockIdx.x * blockDim.x + threadIdx.x;
    if (i < n4) ((float4*)p)[i] = make_float4(0.f, 0.f, 0.f, 0.f);
}

// ---------------- fp32 -> bf16 weight convert (all 4 weights, y = which) --------
// wo (y==3) gets sig64-permuted k-columns to match o_t's sig64 c-layout.
__global__ void cvt4_kernel(const float* __restrict__ wa, const float* __restrict__ wb,
                            const float* __restrict__ wc, const float* __restrict__ wd,
                            unsigned short* __restrict__ out) {
    const float* ins[4] = {wa, wb, wc, wd};
    const float* in = ins[blockIdx.y];
    unsigned short* o = out + (size_t)blockIdx.y * 262144;
    int i = blockIdx.x * blockDim.x + threadIdx.x; // 0..65535 float4s
    float4 v = ((const float4*)in)[i];
    int e = i * 4;
    int idx;
    if (blockIdx.y == 3) {
        int m = e >> 9, k = e & 511;           // k&3 == 0
        int kp = (k & ~63) | (((k >> 2) & 3) << 4) | (((k >> 4) & 3) << 2);
        idx = m * 512 + kp;
    } else {
        idx = e;
    }
    o[idx + 0] = f2bf(v.x);
    o[idx + 1] = f2bf(v.y);
    o[idx + 2] = f2bf(v.z);
    o[idx + 3] = f2bf(v.w);
}

// ---------------- GN pass 1: partial sums per (b,g), 8 sub-blocks each ----------
__global__ void gn_stats_kernel(const float* __restrict__ x, float* __restrict__ sums,
                                float* __restrict__ sqs) {
    int bid = blockIdx.x;          // 1024 = 128 bg * 8 sub
    int bg = bid >> 3, sub = bid & 7;
    const float4* s4 = (const float4*)(x + (size_t)bg * 65536) + sub * 2048;
    int t = threadIdx.x; // 256
    float s1 = 0.f, s2 = 0.f;
#pragma unroll
    for (int k = 0; k < 8; ++k) {
        float4 v = s4[k * 256 + t];
        s1 += v.x + v.y + v.z + v.w;
        s2 += v.x * v.x + v.y * v.y + v.z * v.z + v.w * v.w;
    }
#pragma unroll
    for (int o = 32; o > 0; o >>= 1) { s1 += __shfl_down(s1, o); s2 += __shfl_down(s2, o); }
    __shared__ float r1[4], r2[4];
    int wv_ = t >> 6, ln = t & 63;
    if (ln == 0) { r1[wv_] = s1; r2[wv_] = s2; }
    __syncthreads();
    if (t == 0) {
        atomicAdd(&sums[bg], r1[0] + r1[1] + r1[2] + r1[3]);
        atomicAdd(&sqs[bg], r2[0] + r2[1] + r2[2] + r2[3]);
    }
}

// ---------------- GN pass 2: normalize + transpose via LDS tile ----------------
__global__ __launch_bounds__(256) void gn_norm_kernel(
    const float* __restrict__ x, const float* __restrict__ sums, const float* __restrict__ sqs,
    const float* __restrict__ gamma, const float* __restrict__ beta,
    unsigned short* __restrict__ h_t) {
    __shared__ float tile[64][65];
    int n0 = blockIdx.x * 64, c0 = blockIdx.y * 64, b = blockIdx.z;
    int t = threadIdx.x;
    const float* xb = x + (size_t)b * Cc * Nn;
#pragma unroll
    for (int j = 0; j < 4; ++j) {
        int i = j * 256 + t;
        int c = i >> 4;       // 0..63
        int n4 = i & 15;      // float4 index within row
        int cg = c0 + c;
        float4 v = ((const float4*)(xb + (size_t)cg * Nn + n0))[n4];
        int g = cg >> 4;
        float sm = sums[b * 32 + g], sq = sqs[b * 32 + g];
        float mean = sm * (1.f / 65536.f);
        float var = sq * (1.f / 65536.f) - mean * mean;
        float rs = rsqrtf(var + 1e-6f);
        float ga = gamma[cg] * rs;
        float be = beta[cg] - mean * ga;
        tile[n4 * 4 + 0][c] = v.x * ga + be;
        tile[n4 * 4 + 1][c] = v.y * ga + be;
        tile[n4 * 4 + 2][c] = v.z * ga + be;
        tile[n4 * 4 + 3][c] = v.w * ga + be;
    }
    __syncthreads();
    int n = t >> 2;                 // 0..63
    int cpart = (t & 3) * 16;       // 0,16,32,48
    unsigned short o[16];
#pragma unroll
    for (int q = 0; q < 16; ++q) o[q] = f2bf(tile[n][cpart + q]);
    unsigned short* dst = h_t + (size_t)b * NC + (size_t)(n0 + n) * Cc + c0 + cpart;
    ((uint4*)dst)[0] = ((uint4*)o)[0];
    ((uint4*)dst)[1] = ((uint4*)o)[1];
}

// ---------------- bf16 GEMM: out[M,N] = (A[M,K] * Bt[N,K]^T + bias) * alpha (+res) --------
template <int BM, int DT, int BIAS_MODE, int OUT_MODE, int HAS_RES>
__global__ __launch_bounds__(256, 2) void gemm_bt(
    const unsigned short* __restrict__ A, int lda, size_t sA,
    const unsigned short* __restrict__ Bt, int ldb, size_t sB,
    void* __restrict__ outp, int ldc, size_t sC,
    const float* __restrict__ bias,
    const float* __restrict__ res, size_t sR,
    int K, float alpha,
    const float* __restrict__ bias2, void* __restrict__ outp2, int nsplit) {
    constexpr int MT = BM / 32;  // m-fragments per wave (4 or 8)
    __shared__ unsigned short lA[BM * 64];
    __shared__ unsigned short lB[128 * 64];
    int z = blockIdx.z;
    A += (size_t)z * sA;
    Bt += (size_t)z * sB;
    int m0 = blockIdx.y * BM, n0 = blockIdx.x * 128;
    int ncol0 = n0;
    if (nsplit && n0 >= nsplit) { bias = bias2; outp = outp2; ncol0 = n0 - nsplit; }
    int t = threadIdx.x;
    int lane = t & 63, wave = t >> 6;
    int wm = wave >> 1, wn = wave & 1;
    int lo = lane & 15, quad = lane >> 4;

    f32x4 acc[MT][4];
#pragma unroll
    for (int a1 = 0; a1 < MT; ++a1)
#pragma unroll
        for (int a2 = 0; a2 < 4; ++a2) acc[a1][a2] = (f32x4){0.f, 0.f, 0.f, 0.f};

    for (int k0 = 0; k0 < K; k0 += 64) {
#pragma unroll
        for (int p = 0; p < MT; ++p) {
            int ci = p * 256 + t;
            int row = ci >> 3;
            int gs = (ci ^ row) & 7;  // swizzled granule
            gll16(A + (size_t)(m0 + row) * lda + k0 + gs * 8, &lA[(size_t)ci * 8]);
        }
#pragma unroll
        for (int p = 0; p < 4; ++p) {
            int ci = p * 256 + t;
            int row = ci >> 3;
            int gs = (ci ^ row) & 7;
            gll16(Bt + (size_t)(n0 + row) * ldb + k0 + gs * 8, &lB[(size_t)ci * 8]);
        }
        __syncthreads();
#pragma unroll
        for (int ks = 0; ks < 2; ++ks) {
            int G = quad + ks * 4;  // granule index (8 halfs each)
            bf16x8 af[MT], bfr[4];
#pragma unroll
            for (int mt = 0; mt < MT; ++mt) {
                int R = wm * (BM / 2) + mt * 16 + lo;
                af[mt] = *(const bf16x8*)&lA[R * 64 + (((G ^ R) & 7) << 3)];
            }
#pragma unroll
            for (int nt = 0; nt < 4; ++nt) {
                int R = wn * 64 + nt * 16 + lo;
                bfr[nt] = *(const bf16x8*)&lB[R * 64 + (((G ^ R) & 7) << 3)];
            }
#pragma unroll
            for (int mt = 0; mt < MT; ++mt)
#pragma unroll
                for (int nt = 0; nt < 4; ++nt) {
                    if (DT == 0)
                        acc[mt][nt] = __builtin_amdgcn_mfma_f32_16x16x32_bf16(af[mt], bfr[nt], acc[mt][nt], 0, 0, 0);
                    else
                        acc[mt][nt] = __builtin_amdgcn_mfma_f32_16x16x32_f16(
                            __builtin_bit_cast(f16x8, af[mt]), __builtin_bit_cast(f16x8, bfr[nt]),
                            acc[mt][nt], 0, 0, 0);
                }
        }
        __syncthreads();
    }

    size_t zc = (size_t)z * sC;
    float* outf = (float*)outp + zc;
    unsigned short* outb = (unsigned short*)outp + zc;
    unsigned char* outc = (unsigned char*)outp + zc;
    const float* resz = HAS_RES ? res + (size_t)z * sR : nullptr;

#pragma unroll
    for (int mt = 0; mt < MT; ++mt) {
#pragma unroll
        for (int nt = 0; nt < 4; ++nt) {
            int row = m0 + wm * (BM / 2) + mt * 16 + quad * 4;
            int col = ncol0 + wn * 64 + nt * 16 + lo;
            float bn = (BIAS_MODE == 2) ? bias[col] : 0.f;
#pragma unroll
            for (int r = 0; r < 4; ++r) {
                float vv = acc[mt][nt][r];
                if (BIAS_MODE == 1) vv += bias[row + r];
                if (BIAS_MODE == 2) vv += bn;
                vv *= alpha;
                if (OUT_MODE == 3 || OUT_MODE == 4) {
                    float e = fmaxf(fminf(vv, 448.f), -448.f);
                    int pk = __builtin_amdgcn_cvt_pk_fp8_f32(e, e, 0, false);
                    int cp = (OUT_MODE == 4) ? sig64(col) : col;
                    outc[(size_t)(row + r) * ldc + cp] = (unsigned char)(pk & 0xff);
                } else {
                    size_t off = (size_t)(row + r) * ldc + col;
                    if (HAS_RES) vv += resz[off];
                    if (OUT_MODE == 0) outf[off] = vv;
                    else if (OUT_MODE == 1) outb[off] = f2bf(vv);
                    else outb[off] = f2h(vv);
                }
            }
        }
    }
}

// ---------------- QK: S = fp8(exp((Q.K^T)*alpha - 2)), sig64 j-layout ----------------
// (round-10 exact: no setprio — r11's setprio bundle coincided with regression)
__global__ __launch_bounds__(256, 3) void qk_fp8(
    const unsigned char* __restrict__ Q, const unsigned char* __restrict__ Kt,
    unsigned char* __restrict__ S, float alpha) {
    __shared__ unsigned char lA[128 * 128]; // Q tile, 16 KB
    __shared__ unsigned char lB[128 * 128]; // K tile, 16 KB
    int z = blockIdx.z;
    Q += (size_t)z * NC;
    Kt += (size_t)z * NC;
    S += (size_t)z * SN;
    int m0 = blockIdx.y * 128, n0 = blockIdx.x * 128;
    int t = threadIdx.x;
    int lane = t & 63, wave = t >> 6;
    int wm = wave >> 1, wn = wave & 1;
    int lo = lane & 15, quad = lane >> 4;

    f32x4 acc[4][4]; // [jt][qt]
#pragma unroll
    for (int a1 = 0; a1 < 4; ++a1)
#pragma unroll
        for (int a2 = 0; a2 < 4; ++a2) acc[a1][a2] = (f32x4){0.f, 0.f, 0.f, 0.f};

    for (int k0 = 0; k0 < Cc; k0 += 128) {
#pragma unroll
        for (int p = 0; p < 4; ++p) {
            int ci = p * 256 + t;
            int row = ci >> 3, g = ci & 7;
            int gs = g ^ (row & 7);
            gll16(Q + (size_t)(m0 + row) * Cc + k0 + gs * 16, &lA[ci * 16]);
        }
#pragma unroll
        for (int p = 0; p < 4; ++p) {
            int ci = p * 256 + t;
            int row = ci >> 3, g = ci & 7;
            int gs = g ^ (row & 7);
            gll16(Kt + (size_t)(n0 + row) * Cc + k0 + gs * 16, &lB[ci * 16]);
        }
        __syncthreads();
        int g0 = quad * 2;  // lane quad consumes k-bytes [quad*32, quad*32+32)
        i32x8 qf[4];        // B-operand: Q fragments
#pragma unroll
        for (int qt = 0; qt < 4; ++qt) qf[qt] = ld_frag256(lA, wm * 64 + qt * 16 + lo, g0);
#pragma unroll
        for (int jt = 0; jt < 4; ++jt) {
            i32x8 kf = ld_frag256(lB, wn * 64 + jt * 16 + lo, g0); // A-operand: K fragment
#pragma unroll
            for (int qt = 0; qt < 4; ++qt)
                acc[jt][qt] = mfma_fp8_k128v(kf, qf[qt], acc[jt][qt]);
        }
        __syncthreads();
    }

    // Epilogue: lane (lo,quad) holds S[q][j]; under sig64 those 16 values are bytes
    // [quad*16, quad*16+16) of the 64-group -> one uint4 store per qt.
    const float L2E = 1.4426950408889634f;
    float a2 = alpha * L2E;
    float b2 = -2.f * L2E;
#pragma unroll
    for (int qt = 0; qt < 4; ++qt) {
        int q = m0 + wm * 64 + qt * 16 + lo;
        uint w[4];
#pragma unroll
        for (int jt = 0; jt < 4; ++jt) {
            float e0 = fminf(exp2f(fmaf(acc[jt][qt][0], a2, b2)), 448.f);
            float e1 = fminf(exp2f(fmaf(acc[jt][qt][1], a2, b2)), 448.f);
            float e2 = fminf(exp2f(fmaf(acc[jt][qt][2], a2, b2)), 448.f);
            float e3 = fminf(exp2f(fmaf(acc[jt][qt][3], a2, b2)), 448.f);
            int d = __builtin_amdgcn_cvt_pk_fp8_f32(e0, e1, 0, false);
            d = __builtin_amdgcn_cvt_pk_fp8_f32(e2, e3, d, true);
            w[jt] = (uint)d;
        }
        *(uint4*)&S[(size_t)q * Nn + n0 + wn * 64 + quad * 16] =
            make_uint4(w[0], w[1], w[2], w[3]);
    }
}

// ---------------- PV: o_t[q,c] = (sum_j P[q,j] V[c,j]) / rowsum(P[q,:]) ----------------
// S,V sig64 j-layout; o_t sig64 c-layout. Row sums via ones-MFMA. No setprio.
// XCD-grouping block swizzle: the 4 n-blocks sharing one S panel get flat ids with
// equal residue mod 8 -> same XCD's L2 -> S fetched ~once (r11: 150MB, 2x ideal).
__global__ __launch_bounds__(256, 3) void pv_fp8(
    const unsigned char* __restrict__ S, const unsigned char* __restrict__ V,
    unsigned short* __restrict__ o_t) {
    __shared__ unsigned char lA[128 * 128]; // S tile (q rows)
    __shared__ unsigned char lB[128 * 128]; // V tile (c rows)
    int flat = blockIdx.x + (blockIdx.y << 2) + (blockIdx.z << 7); // [0,512)
    int rr = flat & 7, qq = flat >> 3;
    int member = qq & 3;               // n-block (shares S panel)
    int g = (qq >> 2) * 8 + rr;        // S panel id [0,128)
    int z = g >> 5;
    int m0 = (g & 31) << 7;
    int n0 = member << 7;
    S += (size_t)z * SN;
    V += (size_t)z * NC;
    o_t += (size_t)z * NC;
    int t = threadIdx.x;
    int lane = t & 63, wave = t >> 6;
    int wm = wave >> 1, wn = wave & 1;
    int lo = lane & 15, quad = lane >> 4;

    f32x4 acc[4][4]; // [ct][qt]
    f32x4 rs[4];     // [qt] row-sum accumulators
#pragma unroll
    for (int a1 = 0; a1 < 4; ++a1) {
        rs[a1] = (f32x4){0.f, 0.f, 0.f, 0.f};
#pragma unroll
        for (int a2 = 0; a2 < 4; ++a2) acc[a1][a2] = (f32x4){0.f, 0.f, 0.f, 0.f};
    }
    const int OB = 0x38383838; // 4x fp8 e4m3 1.0
    const i32x8 ones = {OB, OB, OB, OB, OB, OB, OB, OB};

    for (int k0 = 0; k0 < Nn; k0 += 128) {
#pragma unroll
        for (int p = 0; p < 4; ++p) {
            int ci = p * 256 + t;
            int row = ci >> 3, g2 = ci & 7;
            int gs = g2 ^ (row & 7);
            gll16(S + (size_t)(m0 + row) * Nn + k0 + gs * 16, &lA[ci * 16]);
        }
#pragma unroll
        for (int p = 0; p < 4; ++p) {
            int ci = p * 256 + t;
            int row = ci >> 3, g2 = ci & 7;
            int gs = g2 ^ (row & 7);
            gll16(V + (size_t)(n0 + row) * Nn + k0 + gs * 16, &lB[ci * 16]);
        }
        __syncthreads();
        int g0 = quad * 2;
        i32x8 sf[4]; // B-operand: S fragments (q rows)
#pragma unroll
        for (int qt = 0; qt < 4; ++qt) {
            sf[qt] = ld_frag256(lA, wm * 64 + qt * 16 + lo, g0);
            rs[qt] = mfma_fp8_k128v(ones, sf[qt], rs[qt]);
        }
#pragma unroll
        for (int ct = 0; ct < 4; ++ct) {
            i32x8 vf = ld_frag256(lB, wn * 64 + ct * 16 + lo, g0); // A-operand: V fragment
#pragma unroll
            for (int qt = 0; qt < 4; ++qt)
                acc[ct][qt] = mfma_fp8_k128v(vf, sf[qt], acc[ct][qt]);
        }
        __syncthreads();
    }

    // Epilogue: lane's 16 bf16 contiguous under sig64 c-layout -> 2x uint4 per qt.
#pragma unroll
    for (int qt = 0; qt < 4; ++qt) {
        int q = m0 + wm * 64 + qt * 16 + lo;
        float inv = 1.f / rs[qt][0];
        unsigned short o16[16];
#pragma unroll
        for (int ct = 0; ct < 4; ++ct)
#pragma unroll
            for (int r = 0; r < 4; ++r)
                o16[ct * 4 + r] = f2bf(acc[ct][qt][r] * inv);
        unsigned short* dst = &o_t[(size_t)q * Cc + n0 + wn * 64 + quad * 16];
        ((uint4*)dst)[0] = ((uint4*)o16)[0];
        ((uint4*)dst)[1] = ((uint4*)o16)[1];
    }
}

extern "C" void kernel_launch(void* const* d_in, const int* in_sizes, int n_in,
                              void* d_out, int out_size, void* d_ws, size_t ws_size,
                              hipStream_t stream) {
    const float* x     = (const float*)d_in[0];
    const float* gamma = (const float*)d_in[1];
    const float* beta  = (const float*)d_in[2];
    const float* wq = (const float*)d_in[3];
    const float* bq = (const float*)d_in[4];
    const float* wk = (const float*)d_in[5];
    const float* bk = (const float*)d_in[6];
    const float* wv = (const float*)d_in[7];
    const float* bv = (const float*)d_in[8];
    const float* wo = (const float*)d_in[9];
    const float* bo = (const float*)d_in[10];

    char* ws = (char*)d_ws;
    unsigned short* h_t  = (unsigned short*)(ws);                 // [B,N,C] bf16 16MB
    unsigned char*  q_8  = (unsigned char*)(ws + 16777216);       // [B,N,C] fp8
    unsigned char*  k_8  = (unsigned char*)(ws + 33554432);       // [B,N,C] fp8
    unsigned char*  v_8  = (unsigned char*)(ws + 50331648);       // [B,C,N] fp8 sig64
    unsigned short* o_t  = (unsigned short*)(ws + 67108864);      // [B,N,C] bf16 sig64-c
    unsigned char*  S    = (unsigned char*)(ws + 83886080);       // [B,N,N] fp8 sig64 67MB
    unsigned short* wqb  = (unsigned short*)(ws + 218103808);     // wq,wk,wv,wo bf16 contiguous
    unsigned short* wvb  = (unsigned short*)(ws + 219152384);
    unsigned short* wob  = (unsigned short*)(ws + 219676672);     // sig64-k layout
    float* statm         = (float*)(ws + 220200960);              // [128] GN sum
    float* statr         = (float*)(ws + 220201984);              // [128] GN sumsq

    const float SCALE = 0.044194173824159216f; // 512^-0.5

    zero_kernel<<<1, 128, 0, stream>>>(statm, 128); // zeroes statm..statr (2 KB)

    // all 4 weight converts in one launch (wqb/wkb/wvb/wob contiguous, 262144 elems apart)
    cvt4_kernel<<<dim3(256, 4), 256, 0, stream>>>(wq, wk, wv, wo, wqb);

    gn_stats_kernel<<<1024, 256, 0, stream>>>(x, statm, statr);
    gn_norm_kernel<<<dim3(64, 8, 4), 256, 0, stream>>>(x, statm, statr, gamma, beta, h_t);

    // q_8 | k_8 = fp8(h . [Wq;Wk]^T + [bq;bk])  [B,N,C] in ONE launch (col split at 512)
    gemm_bt<128, 0, 2, 3, 0><<<dim3(8, 32, 4), 256, 0, stream>>>(
        h_t, Cc, NC, wqb, Cc, 0, q_8, Cc, NC, bq, nullptr, 0, Cc, 1.f, bk, k_8, 512);
    // v_8 = fp8(Wv . h^T + bv)   [B,C,N] sig64 j-layout (matches S)
    gemm_bt<128, 0, 1, 4, 0><<<dim3(32, 4, 4), 256, 0, stream>>>(
        wvb, Cc, 0, h_t, Cc, NC, v_8, Nn, NC, bv, nullptr, 0, Cc, 1.f, nullptr, nullptr, 0);

    // S = fp8(exp(q.k^T * scale - 2)), sig64 j-layout
    qk_fp8<<<dim3(32, 32, 4), 256, 0, stream>>>(q_8, k_8, S, SCALE);
    // o_t = (S . V^T) / rowsum(S)   bf16 [B,N,C] sig64-c  (row sums via ones-MFMA)
    pv_fp8<<<dim3(4, 32, 4), 256, 0, stream>>>(S, v_8, o_t);

    // out = Wo . o^T + bo + x   fp32 [B,C,N]  (wob and o_t share sig64 k-layout)
    gemm_bt<128, 0, 1, 0, 1><<<dim3(32, 4, 4), 256, 0, stream>>>(
        wob, Cc, 0, o_t, Cc, NC, d_out, Nn, NC, bo, x, NC, Cc, 1.f, nullptr, nullptr, 0);
}